// Round 5
// baseline (385.166 us; speedup 1.0000x reference)
//
#include <hip/hip_runtime.h>
#include <hip/hip_bf16.h>
#include <cstdint>
#include <math.h>

// Problem constants: B=2, S=2048, D=768, H=12, Hd=64
#define DIM   768

typedef __bf16 bf16x8 __attribute__((ext_vector_type(8)));
typedef float f32x4 __attribute__((ext_vector_type(4)));
typedef unsigned short u16x8 __attribute__((ext_vector_type(8)));
typedef unsigned short u16x4 __attribute__((ext_vector_type(4)));

static __device__ __forceinline__ unsigned short f2bf(float f) {
  union { float f; unsigned u; } a; a.f = f;
  unsigned u = a.u;
  u += 0x7fffu + ((u >> 16) & 1u);   // RNE
  return (unsigned short)(u >> 16);
}
static __device__ __forceinline__ unsigned pk2(float a, float b) {
  return (unsigned)f2bf(a) | ((unsigned)f2bf(b) << 16);
}

static __device__ __forceinline__ f32x4 mfma16(bf16x8 a, bf16x8 b, f32x4 c) {
  return __builtin_amdgcn_mfma_f32_16x16x32_bf16(a, b, c, 0, 0, 0);
}

static __device__ __forceinline__ bf16x8 ld_bf8(const unsigned short* p) {
  return *reinterpret_cast<const bf16x8*>(p);
}

static __device__ __forceinline__ void gload_lds16(const void* g, void* l) {
  __builtin_amdgcn_global_load_lds(
      (const __attribute__((address_space(1))) void*)g,
      (__attribute__((address_space(3))) void*)l, 16, 0, 0);
}

#define EXP2 __builtin_amdgcn_exp2f

// ---------------- convert x: fp32 -> bf16 ----------------
__global__ void k_cvt_x(const float* __restrict__ x, unsigned short* __restrict__ xb) {
  int i = (blockIdx.x * 256 + threadIdx.x) * 4;
  float4 v = *reinterpret_cast<const float4*>(x + i);
  u16x4 o;
  o[0] = f2bf(v.x); o[1] = f2bf(v.y); o[2] = f2bf(v.z); o[3] = f2bf(v.w);
  *reinterpret_cast<u16x4*>(xb + i) = o;
}

// ---------------- transpose + convert weights ----------------
__global__ void k_tw(const float* __restrict__ Wq, const float* __restrict__ Wk,
                     const float* __restrict__ Wv, const float* __restrict__ Wo,
                     unsigned short* __restrict__ wqkvt, unsigned short* __restrict__ wot) {
  __shared__ unsigned short tile[64][68];
  const int wsel = blockIdx.z;
  const float* W = wsel == 0 ? Wq : wsel == 1 ? Wk : wsel == 2 ? Wv : Wo;
  const int n0 = blockIdx.x * 64, k0 = blockIdx.y * 64;
  const int t = threadIdx.x;
  const int kr = t >> 4, nc = (t & 15) * 4;
  for (int p = 0; p < 4; ++p) {
    int kk = kr + p * 16;
    float4 v = *reinterpret_cast<const float4*>(W + (size_t)(k0 + kk) * DIM + n0 + nc);
    tile[kk][nc]     = f2bf(v.x);
    tile[kk][nc + 1] = f2bf(v.y);
    tile[kk][nc + 2] = f2bf(v.z);
    tile[kk][nc + 3] = f2bf(v.w);
  }
  __syncthreads();
  const int nr = t >> 3, kc = (t & 7) * 8;
  for (int p = 0; p < 2; ++p) {
    int nn = nr + p * 32;
    u16x8 o;
    for (int j = 0; j < 8; ++j) o[j] = tile[kc + j][nn];
    unsigned short* dst = (wsel < 3)
        ? wqkvt + (size_t)(wsel * DIM + n0 + nn) * DIM + k0 + kc
        : wot + (size_t)(n0 + nn) * DIM + k0 + kc;
    *reinterpret_cast<u16x8*>(dst) = o;
  }
}

// ---------------- GEMM: C[M x N] = A[M x 768] * Bt[N x 768]^T ----------------
// EPI 0: scatter to Q (pre-scaled by (1/8)*log2e) / K [BH][S][64], V^T [BH][64][S]
// EPI 1: fp32 row-major out
template <int EPI>
__global__ __launch_bounds__(256, 2) void k_gemm(
    const unsigned short* __restrict__ A, const unsigned short* __restrict__ Bt,
    unsigned short* __restrict__ qws, unsigned short* __restrict__ kws,
    unsigned short* __restrict__ vtws, float* __restrict__ out) {
  __shared__ alignas(16) unsigned short lA[128 * 64];
  __shared__ alignas(16) unsigned short lB[128 * 64];
  const int t = threadIdx.x;
  const int lane = t & 63, w = t >> 6;
  const int wr = w >> 1, wc = w & 1;
  const int r15 = lane & 15, rhi = lane >> 4;
  const int m0 = blockIdx.x * 128, n0 = blockIdx.y * 128;

  f32x4 acc[4][4] = {};

  for (int kt = 0; kt < 12; ++kt) {
    const int k0 = kt * 64;
    for (int i = 0; i < 4; ++i) {
      int f = i * 256 + t;
      int row = f >> 3;
      int cb = (f & 7) ^ (row & 7);
      gload_lds16(A + (size_t)(m0 + row) * DIM + k0 + cb * 8, (char*)lA + f * 16);
      gload_lds16(Bt + (size_t)(n0 + row) * DIM + k0 + cb * 8, (char*)lB + f * 16);
    }
    __syncthreads();
    for (int kk = 0; kk < 2; ++kk) {
      bf16x8 av[4], bv[4];
      for (int m = 0; m < 4; ++m) {
        int row = wr * 64 + m * 16 + r15;
        int cb = (kk * 4 + rhi) ^ (row & 7);
        av[m] = ld_bf8(lA + row * 64 + cb * 8);
      }
      for (int n = 0; n < 4; ++n) {
        int row = wc * 64 + n * 16 + r15;
        int cb = (kk * 4 + rhi) ^ (row & 7);
        bv[n] = ld_bf8(lB + row * 64 + cb * 8);
      }
      for (int m = 0; m < 4; ++m)
        for (int n = 0; n < 4; ++n)
          acc[m][n] = mfma16(av[m], bv[n], acc[m][n]);
    }
    __syncthreads();
  }

  const float QSC = 0.18033688011112042f;  // (1/8) * log2(e), folded into Q
  for (int m = 0; m < 4; ++m) {
    for (int n = 0; n < 4; ++n) {
      for (int r = 0; r < 4; ++r) {
        int row = m0 + wr * 64 + m * 16 + rhi * 4 + r;   // token index
        int col = n0 + wc * 64 + n * 16 + r15;           // output feature
        float v = acc[m][n][r];
        if (EPI == 0) {
          int wsel = col >= 1536 ? 2 : (col >= 768 ? 1 : 0);
          int c = col - wsel * 768;
          int h = c >> 6, d = c & 63;
          int b = row >> 11, s = row & 2047;
          size_t bh = (size_t)b * 12 + h;
          if (wsel == 0)      qws[(bh * 2048 + s) * 64 + d] = f2bf(v * QSC);
          else if (wsel == 1) kws[(bh * 2048 + s) * 64 + d] = f2bf(v);
          else                vtws[(bh * 64 + d) * 2048 + s] = f2bf(v);
        } else {
          out[(size_t)row * DIM + col] = v;
        }
      }
    }
  }
}

// ---------------- flash attention: staged LDS + swapped-operand 16x16 ----------
// grid (S/64, B*H); 4 waves, each owns 16 q-rows. KV tiles of 64, staged in LDS.
// QK swapped: S^T[kj][q] = mfma16(K_frag, Q_frag); lane(l) holds q = l&15,
//   kj = n*16 + (l>>4)*4 + r  -> per-lane row softmax (2 shfl_xor only).
// PV swapped: O^T[d][q] = mfma16(V^T_frag, P_frag); rescale is per-lane scalar.
__global__ __launch_bounds__(256) void k_attn(
    const unsigned short* __restrict__ qws, const unsigned short* __restrict__ kws,
    const unsigned short* __restrict__ vtws, unsigned short* __restrict__ ows) {
  __shared__ alignas(16) unsigned short lK[64 * 64];     // [kj][d], swizzled
  __shared__ alignas(16) unsigned short lV[64 * 64];     // [d][kj], swizzled
  __shared__ alignas(16) unsigned short lP[4][16 * 72];  // per-wave P[q][kj], pad 8
  const int t = threadIdx.x;
  const int lane = t & 63, w = t >> 6;
  const int r15 = lane & 15, rhi = lane >> 4;
  const int bh = blockIdx.y;
  const int q0 = blockIdx.x * 64 + w * 16;

  // Q fragment: Q[q=r15][d = rhi*8.. / 32+rhi*8..]  (Q pre-scaled by SC)
  const size_t qrow = ((size_t)bh * 2048 + q0 + r15) * 64;
  bf16x8 qa0 = ld_bf8(qws + qrow + rhi * 8);
  bf16x8 qa1 = ld_bf8(qws + qrow + 32 + rhi * 8);

  // O^T accumulator: oaccT[nd][r] = O[q = r15][d = nd*16 + rhi*4 + r]
  f32x4 oaccT[4] = {};
  float mrun = -INFINITY, lrun = 0.f;   // per-lane (q = r15)

  unsigned short* P = &lP[w][0];
  unsigned* Pw = (unsigned*)P;

  for (int kv = 0; kv < 2048; kv += 64) {
    for (int i = 0; i < 2; ++i) {
      int f = i * 256 + t;
      int row = f >> 3;
      int cb = (f & 7) ^ (row & 7);
      gload_lds16(kws + ((size_t)bh * 2048 + kv + row) * 64 + cb * 8, (char*)lK + f * 16);
      gload_lds16(vtws + ((size_t)bh * 64 + row) * 2048 + kv + cb * 8, (char*)lV + f * 16);
    }
    __syncthreads();

    // S^T = K Q^T : sT[n] reg r = S[kj = n*16 + rhi*4 + r][q = r15]
    f32x4 sT[4];
#pragma unroll
    for (int n = 0; n < 4; ++n) {
      int row = n * 16 + r15;
      bf16x8 b0 = ld_bf8(lK + row * 64 + ((rhi) ^ (row & 7)) * 8);
      bf16x8 b1 = ld_bf8(lK + row * 64 + ((4 + rhi) ^ (row & 7)) * 8);
      f32x4 z = {0.f, 0.f, 0.f, 0.f};
      z = mfma16(b0, qa0, z);
      z = mfma16(b1, qa1, z);
      sT[n] = z;
    }

    // per-lane row softmax (q = r15); cross-lane only over {l, l^16, l^32, l^48}
    float mp = sT[0][0];
#pragma unroll
    for (int n = 0; n < 4; ++n)
      for (int r = 0; r < 4; ++r) mp = fmaxf(mp, sT[n][r]);
    mp = fmaxf(mp, __shfl_xor(mp, 16));
    mp = fmaxf(mp, __shfl_xor(mp, 32));

    float mn = fmaxf(mrun, mp);
    float fac = EXP2(mrun - mn);
    mrun = mn;

    float p[4][4];
    float rs = 0.f;
#pragma unroll
    for (int n = 0; n < 4; ++n)
      for (int r = 0; r < 4; ++r) {
        p[n][r] = EXP2(sT[n][r] - mn);
        rs += p[n][r];
      }
    rs += __shfl_xor(rs, 16);
    rs += __shfl_xor(rs, 32);
    lrun = lrun * fac + rs;

    // P store: row q = r15 (72 u16 = 36 u32 stride), packed u32 pairs (2-way free)
#pragma unroll
    for (int n = 0; n < 4; ++n) {
      int kj = n * 16 + rhi * 4;
      Pw[r15 * 36 + (kj >> 1)]     = pk2(p[n][0], p[n][1]);
      Pw[r15 * 36 + (kj >> 1) + 1] = pk2(p[n][2], p[n][3]);
    }

    // rescale O^T (per-lane scalar fac)
#pragma unroll
    for (int nd = 0; nd < 4; ++nd)
      for (int r = 0; r < 4; ++r) oaccT[nd][r] *= fac;

    // PV swapped: A = V^T[d][kj] frags, B = P[q][kj] frags
    bf16x8 pa0 = ld_bf8(P + r15 * 72 + rhi * 8);
    bf16x8 pa1 = ld_bf8(P + r15 * 72 + 32 + rhi * 8);
#pragma unroll
    for (int nd = 0; nd < 4; ++nd) {
      int row = nd * 16 + r15;
      bf16x8 v0 = ld_bf8(lV + row * 64 + ((rhi) ^ (row & 7)) * 8);
      bf16x8 v1 = ld_bf8(lV + row * 64 + ((4 + rhi) ^ (row & 7)) * 8);
      oaccT[nd] = mfma16(v0, pa0, oaccT[nd]);
      oaccT[nd] = mfma16(v1, pa1, oaccT[nd]);
    }
    __syncthreads();
  }

  // epilogue: lane holds O[q = q0+r15][d = nd*16 + rhi*4 + {0..3}] / lrun
  const int b = bh / 12, h = bh % 12;
  float inv = 1.0f / lrun;
  unsigned short* dst = ows + ((size_t)b * 2048 + q0 + r15) * DIM + h * 64;
#pragma unroll
  for (int nd = 0; nd < 4; ++nd) {
    int d = nd * 16 + rhi * 4;
    *(unsigned*)(dst + d)     = pk2(oaccT[nd][0] * inv, oaccT[nd][1] * inv);
    *(unsigned*)(dst + d + 2) = pk2(oaccT[nd][2] * inv, oaccT[nd][3] * inv);
  }
}

extern "C" void kernel_launch(void* const* d_in, const int* in_sizes, int n_in,
                              void* d_out, int out_size, void* d_ws, size_t ws_size,
                              hipStream_t stream) {
  (void)in_sizes; (void)n_in; (void)out_size;
  const float* x  = (const float*)d_in[0];
  const float* Wq = (const float*)d_in[1];
  const float* Wk = (const float*)d_in[2];
  const float* Wv = (const float*)d_in[3];
  const float* Wo = (const float*)d_in[4];
  float* out = (float*)d_out;

  char* ws = (char*)d_ws;
  unsigned short* xb    = (unsigned short*)(ws);                  // 6291456
  unsigned short* wqkvt = (unsigned short*)(ws + 6291456);        // 3538944
  unsigned short* wot   = (unsigned short*)(ws + 9830400);        // 1179648
  unsigned short* qws   = (unsigned short*)(ws + 11010048);       // 6291456
  unsigned short* kws   = (unsigned short*)(ws + 17301504);       // 6291456
  unsigned short* vtws  = (unsigned short*)(ws + 23592960);       // 6291456
  unsigned short* ows   = (unsigned short*)(ws + 29884416);       // 6291456 -> 36175872 total
  if (ws_size < 36175872u) return;

  k_cvt_x<<<3072, 256, 0, stream>>>(x, xb);
  k_tw<<<dim3(12, 12, 4), 256, 0, stream>>>(Wq, Wk, Wv, Wo, wqkvt, wot);
  k_gemm<0><<<dim3(32, 18), 256, 0, stream>>>(xb, wqkvt, qws, kws, vtws, nullptr);
  k_attn<<<dim3(32, 24), 256, 0, stream>>>(qws, kws, vtws, ows);
  k_gemm<1><<<dim3(32, 6), 256, 0, stream>>>(ows, wot, nullptr, nullptr, nullptr, out);
}

// Round 8
// 177.216 us; speedup vs baseline: 2.1734x; 2.1734x over previous
//
#include <hip/hip_runtime.h>
#include <hip/hip_bf16.h>
#include <cstdint>
#include <math.h>

// Problem constants: B=2, S=2048, D=768, H=12, Hd=64
#define DIM   768

typedef __bf16 bf16x8 __attribute__((ext_vector_type(8)));
typedef float f32x4 __attribute__((ext_vector_type(4)));
typedef unsigned short u16x8 __attribute__((ext_vector_type(8)));
typedef unsigned short u16x4 __attribute__((ext_vector_type(4)));

static __device__ __forceinline__ unsigned short f2bf(float f) {
  union { float f; unsigned u; } a; a.f = f;
  unsigned u = a.u;
  u += 0x7fffu + ((u >> 16) & 1u);   // RNE
  return (unsigned short)(u >> 16);
}
static __device__ __forceinline__ unsigned pk2(float a, float b) {
  return (unsigned)f2bf(a) | ((unsigned)f2bf(b) << 16);
}

static __device__ __forceinline__ f32x4 mfma16(bf16x8 a, bf16x8 b, f32x4 c) {
  return __builtin_amdgcn_mfma_f32_16x16x32_bf16(a, b, c, 0, 0, 0);
}

static __device__ __forceinline__ bf16x8 ld_bf8(const unsigned short* p) {
  return *reinterpret_cast<const bf16x8*>(p);
}

static __device__ __forceinline__ void gload_lds16(const void* g, void* l) {
  __builtin_amdgcn_global_load_lds(
      (const __attribute__((address_space(1))) void*)g,
      (__attribute__((address_space(3))) void*)l, 16, 0, 0);
}

#define EXP2 __builtin_amdgcn_exp2f

// ---------------- convert x: fp32 -> bf16 ----------------
__global__ void k_cvt_x(const float* __restrict__ x, unsigned short* __restrict__ xb) {
  int i = (blockIdx.x * 256 + threadIdx.x) * 4;
  float4 v = *reinterpret_cast<const float4*>(x + i);
  u16x4 o;
  o[0] = f2bf(v.x); o[1] = f2bf(v.y); o[2] = f2bf(v.z); o[3] = f2bf(v.w);
  *reinterpret_cast<u16x4*>(xb + i) = o;
}

// ---------------- transpose + convert weights ----------------
// Wq/Wk/Wv -> wqkvt[2304][768] (row n = output feature, col k), Wo -> wot[768][768]
__global__ void k_tw(const float* __restrict__ Wq, const float* __restrict__ Wk,
                     const float* __restrict__ Wv, const float* __restrict__ Wo,
                     unsigned short* __restrict__ wqkvt, unsigned short* __restrict__ wot) {
  __shared__ unsigned short tile[64][68];
  const int wsel = blockIdx.z;
  const float* W = wsel == 0 ? Wq : wsel == 1 ? Wk : wsel == 2 ? Wv : Wo;
  const int n0 = blockIdx.x * 64, k0 = blockIdx.y * 64;
  const int t = threadIdx.x;
  const int kr = t >> 4, nc = (t & 15) * 4;
  for (int p = 0; p < 4; ++p) {
    int kk = kr + p * 16;
    float4 v = *reinterpret_cast<const float4*>(W + (size_t)(k0 + kk) * DIM + n0 + nc);
    tile[kk][nc]     = f2bf(v.x);
    tile[kk][nc + 1] = f2bf(v.y);
    tile[kk][nc + 2] = f2bf(v.z);
    tile[kk][nc + 3] = f2bf(v.w);
  }
  __syncthreads();
  const int nr = t >> 3, kc = (t & 7) * 8;
  for (int p = 0; p < 2; ++p) {
    int nn = nr + p * 32;
    u16x8 o;
    for (int j = 0; j < 8; ++j) o[j] = tile[kc + j][nn];
    unsigned short* dst = (wsel < 3)
        ? wqkvt + (size_t)(wsel * DIM + n0 + nn) * DIM + k0 + kc
        : wot + (size_t)(n0 + nn) * DIM + k0 + kc;
    *reinterpret_cast<u16x8*>(dst) = o;
  }
}

// ---------------- GEMM: C[M x N] = A[M x 768] * Bt[N x 768]^T ----------------
// 128x128 tile, BK=64, 4 waves (2x2), 16x16x32 bf16 MFMA.
// EPI 0: scatter to Q/K [BH][S][64] and V^T [BH][64][S] (bf16)
// EPI 1: fp32 row-major out
// NOTE: byte-identical to the round-1/round-4 version that ran ~60-70 us.
template <int EPI>
__global__ __launch_bounds__(256, 2) void k_gemm(
    const unsigned short* __restrict__ A, const unsigned short* __restrict__ Bt,
    unsigned short* __restrict__ qws, unsigned short* __restrict__ kws,
    unsigned short* __restrict__ vtws, float* __restrict__ out) {
  __shared__ alignas(16) unsigned short lA[128 * 64];
  __shared__ alignas(16) unsigned short lB[128 * 64];
  const int t = threadIdx.x;
  const int lane = t & 63, w = t >> 6;
  const int wr = w >> 1, wc = w & 1;
  const int r15 = lane & 15, rhi = lane >> 4;
  const int m0 = blockIdx.x * 128, n0 = blockIdx.y * 128;

  f32x4 acc[4][4] = {};

  for (int kt = 0; kt < 12; ++kt) {
    const int k0 = kt * 64;
    for (int i = 0; i < 4; ++i) {
      int f = i * 256 + t;            // 16B unit index, 1024 units = 16KB tile
      int row = f >> 3;               // 8 units per 64-elem row
      int cb = (f & 7) ^ (row & 7);   // pre-swizzled source column-block
      gload_lds16(A + (size_t)(m0 + row) * DIM + k0 + cb * 8, (char*)lA + f * 16);
      gload_lds16(Bt + (size_t)(n0 + row) * DIM + k0 + cb * 8, (char*)lB + f * 16);
    }
    __syncthreads();
    for (int kk = 0; kk < 2; ++kk) {
      bf16x8 av[4], bv[4];
      for (int m = 0; m < 4; ++m) {
        int row = wr * 64 + m * 16 + r15;
        int cb = (kk * 4 + rhi) ^ (row & 7);
        av[m] = ld_bf8(lA + row * 64 + cb * 8);
      }
      for (int n = 0; n < 4; ++n) {
        int row = wc * 64 + n * 16 + r15;
        int cb = (kk * 4 + rhi) ^ (row & 7);
        bv[n] = ld_bf8(lB + row * 64 + cb * 8);
      }
      for (int m = 0; m < 4; ++m)
        for (int n = 0; n < 4; ++n)
          acc[m][n] = mfma16(av[m], bv[n], acc[m][n]);
    }
    __syncthreads();
  }

  for (int m = 0; m < 4; ++m) {
    for (int n = 0; n < 4; ++n) {
      for (int r = 0; r < 4; ++r) {
        int row = m0 + wr * 64 + m * 16 + rhi * 4 + r;   // token index
        int col = n0 + wc * 64 + n * 16 + r15;           // output feature
        float v = acc[m][n][r];
        if (EPI == 0) {
          int wsel = col >= 1536 ? 2 : (col >= 768 ? 1 : 0);
          int c = col - wsel * 768;
          int h = c >> 6, d = c & 63;
          int b = row >> 11, s = row & 2047;
          size_t bh = (size_t)b * 12 + h;
          unsigned short bb = f2bf(v);
          if (wsel == 0)      qws[(bh * 2048 + s) * 64 + d] = bb;
          else if (wsel == 1) kws[(bh * 2048 + s) * 64 + d] = bb;
          else                vtws[(bh * 64 + d) * 2048 + s] = bb;
        } else {
          out[(size_t)row * DIM + col] = v;
        }
      }
    }
  }
}

// ---------------- flash attention: staged LDS + swapped-operand 16x16 ----------
// grid (S/64, B*H); 4 waves, each owns 16 q-rows. KV tiles of 64, staged in LDS.
// QK swapped: S^T[kj][q] = mfma16(K_frag, Q_frag); lane(l) holds q = l&15,
//   kj = n*16 + (l>>4)*4 + r  -> per-lane row softmax (2 shfl_xor only).
// PV swapped: O^T[d][q] = mfma16(V^T_frag, P_frag); rescale is per-lane scalar.
__global__ __launch_bounds__(256) void k_attn(
    const unsigned short* __restrict__ qws, const unsigned short* __restrict__ kws,
    const unsigned short* __restrict__ vtws, unsigned short* __restrict__ ows) {
  __shared__ alignas(16) unsigned short lK[64 * 64];     // [kj][d], swizzled
  __shared__ alignas(16) unsigned short lV[64 * 64];     // [d][kj], swizzled
  __shared__ alignas(16) unsigned short lP[4][16 * 72];  // per-wave P[q][kj], pad 8
  const int t = threadIdx.x;
  const int lane = t & 63, w = t >> 6;
  const int r15 = lane & 15, rhi = lane >> 4;
  const int bh = blockIdx.y;
  const int q0 = blockIdx.x * 64 + w * 16;
  const float SC = 0.18033688011112042f;  // (1/8) * log2(e)

  // Q fragment: Q[q=r15][d = rhi*8.. / 32+rhi*8..]
  const size_t qrow = ((size_t)bh * 2048 + q0 + r15) * 64;
  bf16x8 qa0 = ld_bf8(qws + qrow + rhi * 8);
  bf16x8 qa1 = ld_bf8(qws + qrow + 32 + rhi * 8);

  // O^T accumulator: oaccT[nd][r] = O[q = r15][d = nd*16 + rhi*4 + r]
  f32x4 oaccT[4] = {};
  float mrun = -INFINITY, lrun = 0.f;   // per-lane (q = r15)

  unsigned short* P = &lP[w][0];
  unsigned* Pw = (unsigned*)P;

  for (int kv = 0; kv < 2048; kv += 64) {
    for (int i = 0; i < 2; ++i) {
      int f = i * 256 + t;
      int row = f >> 3;
      int cb = (f & 7) ^ (row & 7);
      gload_lds16(kws + ((size_t)bh * 2048 + kv + row) * 64 + cb * 8, (char*)lK + f * 16);
      gload_lds16(vtws + ((size_t)bh * 64 + row) * 2048 + kv + cb * 8, (char*)lV + f * 16);
    }
    __syncthreads();

    // S^T = K Q^T : sT[n] reg r = S[kj = n*16 + rhi*4 + r][q = r15]
    f32x4 sT[4];
#pragma unroll
    for (int n = 0; n < 4; ++n) {
      int row = n * 16 + r15;
      bf16x8 b0 = ld_bf8(lK + row * 64 + ((rhi) ^ (row & 7)) * 8);
      bf16x8 b1 = ld_bf8(lK + row * 64 + ((4 + rhi) ^ (row & 7)) * 8);
      f32x4 z = {0.f, 0.f, 0.f, 0.f};
      z = mfma16(b0, qa0, z);
      z = mfma16(b1, qa1, z);
#pragma unroll
      for (int r = 0; r < 4; ++r) z[r] *= SC;
      sT[n] = z;
    }

    // per-lane row softmax (q = r15); cross-lane only over {l, l^16, l^32, l^48}
    float mp = sT[0][0];
#pragma unroll
    for (int n = 0; n < 4; ++n)
      for (int r = 0; r < 4; ++r) mp = fmaxf(mp, sT[n][r]);
    mp = fmaxf(mp, __shfl_xor(mp, 16));
    mp = fmaxf(mp, __shfl_xor(mp, 32));

    float mn = fmaxf(mrun, mp);
    float fac = EXP2(mrun - mn);
    mrun = mn;

    float p[4][4];
    float rs = 0.f;
#pragma unroll
    for (int n = 0; n < 4; ++n)
      for (int r = 0; r < 4; ++r) {
        p[n][r] = EXP2(sT[n][r] - mn);
        rs += p[n][r];
      }
    rs += __shfl_xor(rs, 16);
    rs += __shfl_xor(rs, 32);
    lrun = lrun * fac + rs;

    // P store: row q = r15 (72 u16 = 36 u32 stride), packed u32 pairs (2-way free)
#pragma unroll
    for (int n = 0; n < 4; ++n) {
      int kj = n * 16 + rhi * 4;
      Pw[r15 * 36 + (kj >> 1)]     = pk2(p[n][0], p[n][1]);
      Pw[r15 * 36 + (kj >> 1) + 1] = pk2(p[n][2], p[n][3]);
    }

    // rescale O^T (per-lane scalar fac)
#pragma unroll
    for (int nd = 0; nd < 4; ++nd)
      for (int r = 0; r < 4; ++r) oaccT[nd][r] *= fac;

    // PV swapped: A = V^T[d][kj] frags, B = P[q][kj] frags
    bf16x8 pa0 = ld_bf8(P + r15 * 72 + rhi * 8);
    bf16x8 pa1 = ld_bf8(P + r15 * 72 + 32 + rhi * 8);
#pragma unroll
    for (int nd = 0; nd < 4; ++nd) {
      int row = nd * 16 + r15;
      bf16x8 v0 = ld_bf8(lV + row * 64 + ((rhi) ^ (row & 7)) * 8);
      bf16x8 v1 = ld_bf8(lV + row * 64 + ((4 + rhi) ^ (row & 7)) * 8);
      oaccT[nd] = mfma16(v0, pa0, oaccT[nd]);
      oaccT[nd] = mfma16(v1, pa1, oaccT[nd]);
    }
    __syncthreads();
  }

  // epilogue: lane holds O[q = q0+r15][d = nd*16 + rhi*4 + {0..3}] / lrun
  const int b = bh / 12, h = bh % 12;
  float inv = 1.0f / lrun;
  unsigned short* dst = ows + ((size_t)b * 2048 + q0 + r15) * DIM + h * 64;
#pragma unroll
  for (int nd = 0; nd < 4; ++nd) {
    int d = nd * 16 + rhi * 4;
    *(unsigned*)(dst + d)     = pk2(oaccT[nd][0] * inv, oaccT[nd][1] * inv);
    *(unsigned*)(dst + d + 2) = pk2(oaccT[nd][2] * inv, oaccT[nd][3] * inv);
  }
}

extern "C" void kernel_launch(void* const* d_in, const int* in_sizes, int n_in,
                              void* d_out, int out_size, void* d_ws, size_t ws_size,
                              hipStream_t stream) {
  (void)in_sizes; (void)n_in; (void)out_size;
  const float* x  = (const float*)d_in[0];
  const float* Wq = (const float*)d_in[1];
  const float* Wk = (const float*)d_in[2];
  const float* Wv = (const float*)d_in[3];
  const float* Wo = (const float*)d_in[4];
  float* out = (float*)d_out;

  char* ws = (char*)d_ws;
  unsigned short* xb    = (unsigned short*)(ws);                  // 6291456
  unsigned short* wqkvt = (unsigned short*)(ws + 6291456);        // 3538944
  unsigned short* wot   = (unsigned short*)(ws + 9830400);        // 1179648
  unsigned short* qws   = (unsigned short*)(ws + 11010048);       // 6291456
  unsigned short* kws   = (unsigned short*)(ws + 17301504);       // 6291456
  unsigned short* vtws  = (unsigned short*)(ws + 23592960);       // 6291456
  unsigned short* ows   = (unsigned short*)(ws + 29884416);       // 6291456 -> 36175872 total
  if (ws_size < 36175872u) return;

  k_cvt_x<<<3072, 256, 0, stream>>>(x, xb);
  k_tw<<<dim3(12, 12, 4), 256, 0, stream>>>(Wq, Wk, Wv, Wo, wqkvt, wot);
  k_gemm<0><<<dim3(32, 18), 256, 0, stream>>>(xb, wqkvt, qws, kws, vtws, nullptr);
  k_attn<<<dim3(32, 24), 256, 0, stream>>>(qws, kws, vtws, ows);
  k_gemm<1><<<dim3(32, 6), 256, 0, stream>>>(ows, wot, nullptr, nullptr, nullptr, out);
}

// Round 9
// 170.439 us; speedup vs baseline: 2.2599x; 1.0398x over previous
//
#include <hip/hip_runtime.h>
#include <hip/hip_bf16.h>
#include <cstdint>
#include <math.h>

// Problem constants: B=2, S=2048, D=768, H=12, Hd=64
#define DIM   768

typedef __bf16 bf16x8 __attribute__((ext_vector_type(8)));
typedef __bf16 bf16x2 __attribute__((ext_vector_type(2)));
typedef float f32x4 __attribute__((ext_vector_type(4)));
typedef unsigned short u16x8 __attribute__((ext_vector_type(8)));
typedef unsigned short u16x4 __attribute__((ext_vector_type(4)));

static __device__ __forceinline__ unsigned short f2bf(float f) {
  union { float f; unsigned u; } a; a.f = f;
  unsigned u = a.u;
  u += 0x7fffu + ((u >> 16) & 1u);   // RNE
  return (unsigned short)(u >> 16);
}
// native pack: compiler emits v_cvt_pk_bf16_f32 (RNE) — ~1 inst vs ~9
static __device__ __forceinline__ unsigned pk2(float a, float b) {
  union { bf16x2 v; unsigned u; } x;
  x.v[0] = (__bf16)a; x.v[1] = (__bf16)b;
  return x.u;
}

static __device__ __forceinline__ f32x4 mfma16(bf16x8 a, bf16x8 b, f32x4 c) {
  return __builtin_amdgcn_mfma_f32_16x16x32_bf16(a, b, c, 0, 0, 0);
}

static __device__ __forceinline__ bf16x8 ld_bf8(const unsigned short* p) {
  return *reinterpret_cast<const bf16x8*>(p);
}

static __device__ __forceinline__ void gload_lds16(const void* g, void* l) {
  __builtin_amdgcn_global_load_lds(
      (const __attribute__((address_space(1))) void*)g,
      (__attribute__((address_space(3))) void*)l, 16, 0, 0);
}

#define EXP2 __builtin_amdgcn_exp2f

// ---------------- convert x: fp32 -> bf16 ----------------
__global__ void k_cvt_x(const float* __restrict__ x, unsigned short* __restrict__ xb) {
  int i = (blockIdx.x * 256 + threadIdx.x) * 4;
  float4 v = *reinterpret_cast<const float4*>(x + i);
  u16x4 o;
  o[0] = f2bf(v.x); o[1] = f2bf(v.y); o[2] = f2bf(v.z); o[3] = f2bf(v.w);
  *reinterpret_cast<u16x4*>(xb + i) = o;
}

// ---------------- transpose + convert weights ----------------
// Wq/Wk/Wv -> wqkvt[2304][768] (row n = output feature, col k), Wo -> wot[768][768]
__global__ void k_tw(const float* __restrict__ Wq, const float* __restrict__ Wk,
                     const float* __restrict__ Wv, const float* __restrict__ Wo,
                     unsigned short* __restrict__ wqkvt, unsigned short* __restrict__ wot) {
  __shared__ unsigned short tile[64][68];
  const int wsel = blockIdx.z;
  const float* W = wsel == 0 ? Wq : wsel == 1 ? Wk : wsel == 2 ? Wv : Wo;
  const int n0 = blockIdx.x * 64, k0 = blockIdx.y * 64;
  const int t = threadIdx.x;
  const int kr = t >> 4, nc = (t & 15) * 4;
  for (int p = 0; p < 4; ++p) {
    int kk = kr + p * 16;
    float4 v = *reinterpret_cast<const float4*>(W + (size_t)(k0 + kk) * DIM + n0 + nc);
    tile[kk][nc]     = f2bf(v.x);
    tile[kk][nc + 1] = f2bf(v.y);
    tile[kk][nc + 2] = f2bf(v.z);
    tile[kk][nc + 3] = f2bf(v.w);
  }
  __syncthreads();
  const int nr = t >> 3, kc = (t & 7) * 8;
  for (int p = 0; p < 2; ++p) {
    int nn = nr + p * 32;
    u16x8 o;
    for (int j = 0; j < 8; ++j) o[j] = tile[kc + j][nn];
    unsigned short* dst = (wsel < 3)
        ? wqkvt + (size_t)(wsel * DIM + n0 + nn) * DIM + k0 + kc
        : wot + (size_t)(n0 + nn) * DIM + k0 + kc;
    *reinterpret_cast<u16x8*>(dst) = o;
  }
}

// ---------------- GEMM: C[M x N] = A[M x 768] * Bt[N x 768]^T ----------------
// 128x128 tile, BK=64, 4 waves (2x2), 16x16x32 bf16 MFMA.
// EPI 0: scatter to Q/K [BH][S][64] and V^T [BH][64][S] (bf16)
// EPI 1: fp32 row-major out
// NOTE: byte-identical to the round-1/round-4/round-8 version. DO NOT EDIT
// the epilogue — the round-5 variant of it triggered a 4x codegen cliff.
template <int EPI>
__global__ __launch_bounds__(256, 2) void k_gemm(
    const unsigned short* __restrict__ A, const unsigned short* __restrict__ Bt,
    unsigned short* __restrict__ qws, unsigned short* __restrict__ kws,
    unsigned short* __restrict__ vtws, float* __restrict__ out) {
  __shared__ alignas(16) unsigned short lA[128 * 64];
  __shared__ alignas(16) unsigned short lB[128 * 64];
  const int t = threadIdx.x;
  const int lane = t & 63, w = t >> 6;
  const int wr = w >> 1, wc = w & 1;
  const int r15 = lane & 15, rhi = lane >> 4;
  const int m0 = blockIdx.x * 128, n0 = blockIdx.y * 128;

  f32x4 acc[4][4] = {};

  for (int kt = 0; kt < 12; ++kt) {
    const int k0 = kt * 64;
    for (int i = 0; i < 4; ++i) {
      int f = i * 256 + t;            // 16B unit index, 1024 units = 16KB tile
      int row = f >> 3;               // 8 units per 64-elem row
      int cb = (f & 7) ^ (row & 7);   // pre-swizzled source column-block
      gload_lds16(A + (size_t)(m0 + row) * DIM + k0 + cb * 8, (char*)lA + f * 16);
      gload_lds16(Bt + (size_t)(n0 + row) * DIM + k0 + cb * 8, (char*)lB + f * 16);
    }
    __syncthreads();
    for (int kk = 0; kk < 2; ++kk) {
      bf16x8 av[4], bv[4];
      for (int m = 0; m < 4; ++m) {
        int row = wr * 64 + m * 16 + r15;
        int cb = (kk * 4 + rhi) ^ (row & 7);
        av[m] = ld_bf8(lA + row * 64 + cb * 8);
      }
      for (int n = 0; n < 4; ++n) {
        int row = wc * 64 + n * 16 + r15;
        int cb = (kk * 4 + rhi) ^ (row & 7);
        bv[n] = ld_bf8(lB + row * 64 + cb * 8);
      }
      for (int m = 0; m < 4; ++m)
        for (int n = 0; n < 4; ++n)
          acc[m][n] = mfma16(av[m], bv[n], acc[m][n]);
    }
    __syncthreads();
  }

  for (int m = 0; m < 4; ++m) {
    for (int n = 0; n < 4; ++n) {
      for (int r = 0; r < 4; ++r) {
        int row = m0 + wr * 64 + m * 16 + rhi * 4 + r;   // token index
        int col = n0 + wc * 64 + n * 16 + r15;           // output feature
        float v = acc[m][n][r];
        if (EPI == 0) {
          int wsel = col >= 1536 ? 2 : (col >= 768 ? 1 : 0);
          int c = col - wsel * 768;
          int h = c >> 6, d = c & 63;
          int b = row >> 11, s = row & 2047;
          size_t bh = (size_t)b * 12 + h;
          unsigned short bb = f2bf(v);
          if (wsel == 0)      qws[(bh * 2048 + s) * 64 + d] = bb;
          else if (wsel == 1) kws[(bh * 2048 + s) * 64 + d] = bb;
          else                vtws[(bh * 64 + d) * 2048 + s] = bb;
        } else {
          out[(size_t)row * DIM + col] = v;
        }
      }
    }
  }
}

// ---------------- flash attention: staged LDS + swapped-operand 16x16 ----------
// grid (B*H, S/64): head = blockIdx.x so head h -> XCD h%8 (3 heads/XCD L2).
// 4 waves, each owns 16 q-rows. KV tiles of 64, staged in LDS.
// QK swapped: S^T[kj][q] = mfma16(K_frag, Q_frag); lane(l) holds q = l&15,
//   kj = n*16 + (l>>4)*4 + r  -> per-lane row softmax (2 shfl_xor only).
// PV swapped: O^T[d][q] = mfma16(V^T_frag, P_frag); rescale is per-lane scalar.
__global__ __launch_bounds__(256) void k_attn(
    const unsigned short* __restrict__ qws, const unsigned short* __restrict__ kws,
    const unsigned short* __restrict__ vtws, unsigned short* __restrict__ ows) {
  __shared__ alignas(16) unsigned short lK[64 * 64];     // [kj][d], swizzled
  __shared__ alignas(16) unsigned short lV[64 * 64];     // [d][kj], swizzled
  __shared__ alignas(16) unsigned short lP[4][16 * 72];  // per-wave P[q][kj], pad 8
  const int t = threadIdx.x;
  const int lane = t & 63, w = t >> 6;
  const int r15 = lane & 15, rhi = lane >> 4;
  const int bh = blockIdx.x;                // head-major: head -> fixed XCD
  const int q0 = blockIdx.y * 64 + w * 16;
  const float SC = 0.18033688011112042f;    // (1/8) * log2(e)

  // Q fragment: Q[q=r15][d = rhi*8.. / 32+rhi*8..]
  const size_t qrow = ((size_t)bh * 2048 + q0 + r15) * 64;
  bf16x8 qa0 = ld_bf8(qws + qrow + rhi * 8);
  bf16x8 qa1 = ld_bf8(qws + qrow + 32 + rhi * 8);

  // O^T accumulator: oaccT[nd][r] = O[q = r15][d = nd*16 + rhi*4 + r]
  f32x4 oaccT[4] = {};
  float mrun = -INFINITY, lrun = 0.f;   // per-lane (q = r15), log2 domain

  unsigned short* P = &lP[w][0];
  unsigned* Pw = (unsigned*)P;

  for (int kv = 0; kv < 2048; kv += 64) {
    for (int i = 0; i < 2; ++i) {
      int f = i * 256 + t;
      int row = f >> 3;
      int cb = (f & 7) ^ (row & 7);
      gload_lds16(kws + ((size_t)bh * 2048 + kv + row) * 64 + cb * 8, (char*)lK + f * 16);
      gload_lds16(vtws + ((size_t)bh * 64 + row) * 2048 + kv + cb * 8, (char*)lV + f * 16);
    }
    __syncthreads();

    // S^T raw = K Q^T : sT[n] reg r = S[kj = n*16 + rhi*4 + r][q = r15]
    f32x4 sT[4];
#pragma unroll
    for (int n = 0; n < 4; ++n) {
      int row = n * 16 + r15;
      bf16x8 b0 = ld_bf8(lK + row * 64 + ((rhi) ^ (row & 7)) * 8);
      bf16x8 b1 = ld_bf8(lK + row * 64 + ((4 + rhi) ^ (row & 7)) * 8);
      f32x4 z = {0.f, 0.f, 0.f, 0.f};
      z = mfma16(b0, qa0, z);
      z = mfma16(b1, qa1, z);
      sT[n] = z;
    }

    // per-lane row max over raw S (monotone under *SC)
    float mp = sT[0][0];
#pragma unroll
    for (int n = 0; n < 4; ++n)
      for (int r = 0; r < 4; ++r) mp = fmaxf(mp, sT[n][r]);
    mp = fmaxf(mp, __shfl_xor(mp, 16));
    mp = fmaxf(mp, __shfl_xor(mp, 32));
    float mps = mp * SC;

    // defer-max (T13): rescale only when max moved > 8 in log2 domain
    if (!__all(mps <= mrun + 8.0f)) {
      float mn = fmaxf(mrun, mps);
      float fac = EXP2(mrun - mn);
      mrun = mn;
      lrun *= fac;
#pragma unroll
      for (int nd = 0; nd < 4; ++nd)
        for (int r = 0; r < 4; ++r) oaccT[nd][r] *= fac;
    }

    // P = exp2(s*SC - m) via fused fma; bounded by 2^8 when deferred
    float p[4][4];
    float rs = 0.f;
#pragma unroll
    for (int n = 0; n < 4; ++n)
      for (int r = 0; r < 4; ++r) {
        p[n][r] = EXP2(fmaf(sT[n][r], SC, -mrun));
        rs += p[n][r];
      }
    rs += __shfl_xor(rs, 16);
    rs += __shfl_xor(rs, 32);
    lrun += rs;

    // P store: row q = r15 (72 u16 = 36 u32 stride), packed u32 pairs
#pragma unroll
    for (int n = 0; n < 4; ++n) {
      int kj = n * 16 + rhi * 4;
      Pw[r15 * 36 + (kj >> 1)]     = pk2(p[n][0], p[n][1]);
      Pw[r15 * 36 + (kj >> 1) + 1] = pk2(p[n][2], p[n][3]);
    }

    // PV swapped: A = V^T[d][kj] frags, B = P[q][kj] frags
    bf16x8 pa0 = ld_bf8(P + r15 * 72 + rhi * 8);
    bf16x8 pa1 = ld_bf8(P + r15 * 72 + 32 + rhi * 8);
#pragma unroll
    for (int nd = 0; nd < 4; ++nd) {
      int row = nd * 16 + r15;
      bf16x8 v0 = ld_bf8(lV + row * 64 + ((rhi) ^ (row & 7)) * 8);
      bf16x8 v1 = ld_bf8(lV + row * 64 + ((4 + rhi) ^ (row & 7)) * 8);
      oaccT[nd] = mfma16(v0, pa0, oaccT[nd]);
      oaccT[nd] = mfma16(v1, pa1, oaccT[nd]);
    }
    __syncthreads();
  }

  // epilogue: lane holds O[q = q0+r15][d = nd*16 + rhi*4 + {0..3}] / lrun
  const int b = bh / 12, h = bh % 12;
  float inv = 1.0f / lrun;
  unsigned short* dst = ows + ((size_t)b * 2048 + q0 + r15) * DIM + h * 64;
#pragma unroll
  for (int nd = 0; nd < 4; ++nd) {
    int d = nd * 16 + rhi * 4;
    *(unsigned*)(dst + d)     = pk2(oaccT[nd][0] * inv, oaccT[nd][1] * inv);
    *(unsigned*)(dst + d + 2) = pk2(oaccT[nd][2] * inv, oaccT[nd][3] * inv);
  }
}

extern "C" void kernel_launch(void* const* d_in, const int* in_sizes, int n_in,
                              void* d_out, int out_size, void* d_ws, size_t ws_size,
                              hipStream_t stream) {
  (void)in_sizes; (void)n_in; (void)out_size;
  const float* x  = (const float*)d_in[0];
  const float* Wq = (const float*)d_in[1];
  const float* Wk = (const float*)d_in[2];
  const float* Wv = (const float*)d_in[3];
  const float* Wo = (const float*)d_in[4];
  float* out = (float*)d_out;

  char* ws = (char*)d_ws;
  unsigned short* xb    = (unsigned short*)(ws);                  // 6291456
  unsigned short* wqkvt = (unsigned short*)(ws + 6291456);        // 3538944
  unsigned short* wot   = (unsigned short*)(ws + 9830400);        // 1179648
  unsigned short* qws   = (unsigned short*)(ws + 11010048);       // 6291456
  unsigned short* kws   = (unsigned short*)(ws + 17301504);       // 6291456
  unsigned short* vtws  = (unsigned short*)(ws + 23592960);       // 6291456
  unsigned short* ows   = (unsigned short*)(ws + 29884416);       // 6291456 -> 36175872 total
  if (ws_size < 36175872u) return;

  k_cvt_x<<<3072, 256, 0, stream>>>(x, xb);
  k_tw<<<dim3(12, 12, 4), 256, 0, stream>>>(Wq, Wk, Wv, Wo, wqkvt, wot);
  k_gemm<0><<<dim3(32, 18), 256, 0, stream>>>(xb, wqkvt, qws, kws, vtws, nullptr);
  k_attn<<<dim3(24, 32), 256, 0, stream>>>(qws, kws, vtws, ows);
  k_gemm<1><<<dim3(32, 6), 256, 0, stream>>>(ows, wot, nullptr, nullptr, nullptr, out);
}

// Round 10
// 170.028 us; speedup vs baseline: 2.2653x; 1.0024x over previous
//
#include <hip/hip_runtime.h>
#include <hip/hip_bf16.h>
#include <cstdint>
#include <math.h>

// Problem constants: B=2, S=2048, D=768, H=12, Hd=64
#define DIM   768

typedef __bf16 bf16x8 __attribute__((ext_vector_type(8)));
typedef __bf16 bf16x2 __attribute__((ext_vector_type(2)));
typedef float f32x4 __attribute__((ext_vector_type(4)));
typedef unsigned short u16x8 __attribute__((ext_vector_type(8)));
typedef unsigned short u16x4 __attribute__((ext_vector_type(4)));

static __device__ __forceinline__ unsigned short f2bf(float f) {
  union { float f; unsigned u; } a; a.f = f;
  unsigned u = a.u;
  u += 0x7fffu + ((u >> 16) & 1u);   // RNE
  return (unsigned short)(u >> 16);
}
// native pack: compiler emits v_cvt_pk_bf16_f32 (RNE) — ~1 inst vs ~9
static __device__ __forceinline__ unsigned pk2(float a, float b) {
  union { bf16x2 v; unsigned u; } x;
  x.v[0] = (__bf16)a; x.v[1] = (__bf16)b;
  return x.u;
}

static __device__ __forceinline__ f32x4 mfma16(bf16x8 a, bf16x8 b, f32x4 c) {
  return __builtin_amdgcn_mfma_f32_16x16x32_bf16(a, b, c, 0, 0, 0);
}

static __device__ __forceinline__ bf16x8 ld_bf8(const unsigned short* p) {
  return *reinterpret_cast<const bf16x8*>(p);
}

static __device__ __forceinline__ void gload_lds16(const void* g, void* l) {
  __builtin_amdgcn_global_load_lds(
      (const __attribute__((address_space(1))) void*)g,
      (__attribute__((address_space(3))) void*)l, 16, 0, 0);
}

#define EXP2 __builtin_amdgcn_exp2f

// ---------------- convert x: fp32 -> bf16 ----------------
__global__ void k_cvt_x(const float* __restrict__ x, unsigned short* __restrict__ xb) {
  int i = (blockIdx.x * 256 + threadIdx.x) * 4;
  float4 v = *reinterpret_cast<const float4*>(x + i);
  u16x4 o;
  o[0] = f2bf(v.x); o[1] = f2bf(v.y); o[2] = f2bf(v.z); o[3] = f2bf(v.w);
  *reinterpret_cast<u16x4*>(xb + i) = o;
}

// ---------------- transpose + convert weights ----------------
// Wq/Wk/Wv -> wqkvt[2304][768] (row n = output feature, col k), Wo -> wot[768][768]
__global__ void k_tw(const float* __restrict__ Wq, const float* __restrict__ Wk,
                     const float* __restrict__ Wv, const float* __restrict__ Wo,
                     unsigned short* __restrict__ wqkvt, unsigned short* __restrict__ wot) {
  __shared__ unsigned short tile[64][68];
  const int wsel = blockIdx.z;
  const float* W = wsel == 0 ? Wq : wsel == 1 ? Wk : wsel == 2 ? Wv : Wo;
  const int n0 = blockIdx.x * 64, k0 = blockIdx.y * 64;
  const int t = threadIdx.x;
  const int kr = t >> 4, nc = (t & 15) * 4;
  for (int p = 0; p < 4; ++p) {
    int kk = kr + p * 16;
    float4 v = *reinterpret_cast<const float4*>(W + (size_t)(k0 + kk) * DIM + n0 + nc);
    tile[kk][nc]     = f2bf(v.x);
    tile[kk][nc + 1] = f2bf(v.y);
    tile[kk][nc + 2] = f2bf(v.z);
    tile[kk][nc + 3] = f2bf(v.w);
  }
  __syncthreads();
  const int nr = t >> 3, kc = (t & 7) * 8;
  for (int p = 0; p < 2; ++p) {
    int nn = nr + p * 32;
    u16x8 o;
    for (int j = 0; j < 8; ++j) o[j] = tile[kc + j][nn];
    unsigned short* dst = (wsel < 3)
        ? wqkvt + (size_t)(wsel * DIM + n0 + nn) * DIM + k0 + kc
        : wot + (size_t)(n0 + nn) * DIM + k0 + kc;
    *reinterpret_cast<u16x8*>(dst) = o;
  }
}

// ---------------- GEMM: C[M x N] = A[M x 768] * Bt[N x 768]^T ----------------
// 128x128 tile, BK=64, 4 waves (2x2), 16x16x32 bf16 MFMA.
// EPI 0: scatter to Q/K [BH][S][64] and V^T [BH][64][S] (bf16)
// EPI 1: fp32 row-major out
// NOTE: byte-identical to the round-1/round-4/round-8 version. DO NOT EDIT
// the epilogue — the round-5 variant of it triggered a 4x codegen cliff.
template <int EPI>
__global__ __launch_bounds__(256, 2) void k_gemm(
    const unsigned short* __restrict__ A, const unsigned short* __restrict__ Bt,
    unsigned short* __restrict__ qws, unsigned short* __restrict__ kws,
    unsigned short* __restrict__ vtws, float* __restrict__ out) {
  __shared__ alignas(16) unsigned short lA[128 * 64];
  __shared__ alignas(16) unsigned short lB[128 * 64];
  const int t = threadIdx.x;
  const int lane = t & 63, w = t >> 6;
  const int wr = w >> 1, wc = w & 1;
  const int r15 = lane & 15, rhi = lane >> 4;
  const int m0 = blockIdx.x * 128, n0 = blockIdx.y * 128;

  f32x4 acc[4][4] = {};

  for (int kt = 0; kt < 12; ++kt) {
    const int k0 = kt * 64;
    for (int i = 0; i < 4; ++i) {
      int f = i * 256 + t;            // 16B unit index, 1024 units = 16KB tile
      int row = f >> 3;               // 8 units per 64-elem row
      int cb = (f & 7) ^ (row & 7);   // pre-swizzled source column-block
      gload_lds16(A + (size_t)(m0 + row) * DIM + k0 + cb * 8, (char*)lA + f * 16);
      gload_lds16(Bt + (size_t)(n0 + row) * DIM + k0 + cb * 8, (char*)lB + f * 16);
    }
    __syncthreads();
    for (int kk = 0; kk < 2; ++kk) {
      bf16x8 av[4], bv[4];
      for (int m = 0; m < 4; ++m) {
        int row = wr * 64 + m * 16 + r15;
        int cb = (kk * 4 + rhi) ^ (row & 7);
        av[m] = ld_bf8(lA + row * 64 + cb * 8);
      }
      for (int n = 0; n < 4; ++n) {
        int row = wc * 64 + n * 16 + r15;
        int cb = (kk * 4 + rhi) ^ (row & 7);
        bv[n] = ld_bf8(lB + row * 64 + cb * 8);
      }
      for (int m = 0; m < 4; ++m)
        for (int n = 0; n < 4; ++n)
          acc[m][n] = mfma16(av[m], bv[n], acc[m][n]);
    }
    __syncthreads();
  }

  for (int m = 0; m < 4; ++m) {
    for (int n = 0; n < 4; ++n) {
      for (int r = 0; r < 4; ++r) {
        int row = m0 + wr * 64 + m * 16 + rhi * 4 + r;   // token index
        int col = n0 + wc * 64 + n * 16 + r15;           // output feature
        float v = acc[m][n][r];
        if (EPI == 0) {
          int wsel = col >= 1536 ? 2 : (col >= 768 ? 1 : 0);
          int c = col - wsel * 768;
          int h = c >> 6, d = c & 63;
          int b = row >> 11, s = row & 2047;
          size_t bh = (size_t)b * 12 + h;
          unsigned short bb = f2bf(v);
          if (wsel == 0)      qws[(bh * 2048 + s) * 64 + d] = bb;
          else if (wsel == 1) kws[(bh * 2048 + s) * 64 + d] = bb;
          else                vtws[(bh * 64 + d) * 2048 + s] = bb;
        } else {
          out[(size_t)row * DIM + col] = v;
        }
      }
    }
  }
}

// ---------------- flash attention: staged LDS + swapped-operand 16x16 ----------
// grid (B*H, S/64): head = blockIdx.x so head h -> XCD h%8 (3 heads/XCD L2).
// 4 waves, each owns 16 q-rows. KV tiles of 64, staged in LDS.
// QK swapped: S^T[kj][q] = mfma16(K_frag, Q_frag); lane(l) holds q = l&15,
//   kj = n*16 + (l>>4)*4 + r  -> per-lane row softmax (2 shfl_xor only).
// PV swapped: O^T[d][q] = mfma16(V^T_frag, P_frag); rescale is per-lane scalar.
__global__ __launch_bounds__(256) void k_attn(
    const unsigned short* __restrict__ qws, const unsigned short* __restrict__ kws,
    const unsigned short* __restrict__ vtws, unsigned short* __restrict__ ows) {
  __shared__ alignas(16) unsigned short lK[64 * 64];     // [kj][d], swizzled
  __shared__ alignas(16) unsigned short lV[64 * 64];     // [d][kj], swizzled
  __shared__ alignas(16) unsigned short lP[4][16 * 72];  // per-wave P[q][kj], pad 8
  const int t = threadIdx.x;
  const int lane = t & 63, w = t >> 6;
  const int r15 = lane & 15, rhi = lane >> 4;
  const int bh = blockIdx.x;                // head-major: head -> fixed XCD
  const int q0 = blockIdx.y * 64 + w * 16;
  const float SC = 0.18033688011112042f;    // (1/8) * log2(e)

  // Q fragment: Q[q=r15][d = rhi*8.. / 32+rhi*8..]
  const size_t qrow = ((size_t)bh * 2048 + q0 + r15) * 64;
  bf16x8 qa0 = ld_bf8(qws + qrow + rhi * 8);
  bf16x8 qa1 = ld_bf8(qws + qrow + 32 + rhi * 8);

  // O^T accumulator: oaccT[nd][r] = O[q = r15][d = nd*16 + rhi*4 + r]
  f32x4 oaccT[4] = {};
  float mrun = -INFINITY, lrun = 0.f;   // per-lane (q = r15), log2 domain

  unsigned short* P = &lP[w][0];
  unsigned* Pw = (unsigned*)P;

  for (int kv = 0; kv < 2048; kv += 64) {
    for (int i = 0; i < 2; ++i) {
      int f = i * 256 + t;
      int row = f >> 3;
      int cb = (f & 7) ^ (row & 7);
      gload_lds16(kws + ((size_t)bh * 2048 + kv + row) * 64 + cb * 8, (char*)lK + f * 16);
      gload_lds16(vtws + ((size_t)bh * 64 + row) * 2048 + kv + cb * 8, (char*)lV + f * 16);
    }
    __syncthreads();

    // S^T raw = K Q^T : sT[n] reg r = S[kj = n*16 + rhi*4 + r][q = r15]
    f32x4 sT[4];
#pragma unroll
    for (int n = 0; n < 4; ++n) {
      int row = n * 16 + r15;
      bf16x8 b0 = ld_bf8(lK + row * 64 + ((rhi) ^ (row & 7)) * 8);
      bf16x8 b1 = ld_bf8(lK + row * 64 + ((4 + rhi) ^ (row & 7)) * 8);
      f32x4 z = {0.f, 0.f, 0.f, 0.f};
      z = mfma16(b0, qa0, z);
      z = mfma16(b1, qa1, z);
      sT[n] = z;
    }

    // per-lane row max over raw S (monotone under *SC)
    float mp = sT[0][0];
#pragma unroll
    for (int n = 0; n < 4; ++n)
      for (int r = 0; r < 4; ++r) mp = fmaxf(mp, sT[n][r]);
    mp = fmaxf(mp, __shfl_xor(mp, 16));
    mp = fmaxf(mp, __shfl_xor(mp, 32));
    float mps = mp * SC;

    // defer-max (T13): rescale only when max moved > 8 in log2 domain
    if (!__all(mps <= mrun + 8.0f)) {
      float mn = fmaxf(mrun, mps);
      float fac = EXP2(mrun - mn);
      mrun = mn;
      lrun *= fac;
#pragma unroll
      for (int nd = 0; nd < 4; ++nd)
        for (int r = 0; r < 4; ++r) oaccT[nd][r] *= fac;
    }

    // P = exp2(s*SC - m) via fused fma; bounded by 2^8 when deferred
    float p[4][4];
    float rs = 0.f;
#pragma unroll
    for (int n = 0; n < 4; ++n)
      for (int r = 0; r < 4; ++r) {
        p[n][r] = EXP2(fmaf(sT[n][r], SC, -mrun));
        rs += p[n][r];
      }
    rs += __shfl_xor(rs, 16);
    rs += __shfl_xor(rs, 32);
    lrun += rs;

    // P store: row q = r15 (72 u16 = 36 u32 stride), packed u32 pairs
#pragma unroll
    for (int n = 0; n < 4; ++n) {
      int kj = n * 16 + rhi * 4;
      Pw[r15 * 36 + (kj >> 1)]     = pk2(p[n][0], p[n][1]);
      Pw[r15 * 36 + (kj >> 1) + 1] = pk2(p[n][2], p[n][3]);
    }

    // PV swapped: A = V^T[d][kj] frags, B = P[q][kj] frags
    bf16x8 pa0 = ld_bf8(P + r15 * 72 + rhi * 8);
    bf16x8 pa1 = ld_bf8(P + r15 * 72 + 32 + rhi * 8);
#pragma unroll
    for (int nd = 0; nd < 4; ++nd) {
      int row = nd * 16 + r15;
      bf16x8 v0 = ld_bf8(lV + row * 64 + ((rhi) ^ (row & 7)) * 8);
      bf16x8 v1 = ld_bf8(lV + row * 64 + ((4 + rhi) ^ (row & 7)) * 8);
      oaccT[nd] = mfma16(v0, pa0, oaccT[nd]);
      oaccT[nd] = mfma16(v1, pa1, oaccT[nd]);
    }
    __syncthreads();
  }

  // epilogue: lane holds O[q = q0+r15][d = nd*16 + rhi*4 + {0..3}] / lrun
  const int b = bh / 12, h = bh % 12;
  float inv = 1.0f / lrun;
  unsigned short* dst = ows + ((size_t)b * 2048 + q0 + r15) * DIM + h * 64;
#pragma unroll
  for (int nd = 0; nd < 4; ++nd) {
    int d = nd * 16 + rhi * 4;
    *(unsigned*)(dst + d)     = pk2(oaccT[nd][0] * inv, oaccT[nd][1] * inv);
    *(unsigned*)(dst + d + 2) = pk2(oaccT[nd][2] * inv, oaccT[nd][3] * inv);
  }
}

extern "C" void kernel_launch(void* const* d_in, const int* in_sizes, int n_in,
                              void* d_out, int out_size, void* d_ws, size_t ws_size,
                              hipStream_t stream) {
  (void)in_sizes; (void)n_in; (void)out_size;
  const float* x  = (const float*)d_in[0];
  const float* Wq = (const float*)d_in[1];
  const float* Wk = (const float*)d_in[2];
  const float* Wv = (const float*)d_in[3];
  const float* Wo = (const float*)d_in[4];
  float* out = (float*)d_out;

  char* ws = (char*)d_ws;
  unsigned short* xb    = (unsigned short*)(ws);                  // 6291456
  unsigned short* wqkvt = (unsigned short*)(ws + 6291456);        // 3538944
  unsigned short* wot   = (unsigned short*)(ws + 9830400);        // 1179648
  unsigned short* qws   = (unsigned short*)(ws + 11010048);       // 6291456
  unsigned short* kws   = (unsigned short*)(ws + 17301504);       // 6291456
  unsigned short* vtws  = (unsigned short*)(ws + 23592960);       // 6291456
  unsigned short* ows   = (unsigned short*)(ws + 29884416);       // 6291456 -> 36175872 total
  if (ws_size < 36175872u) return;

  k_cvt_x<<<3072, 256, 0, stream>>>(x, xb);
  k_tw<<<dim3(12, 12, 4), 256, 0, stream>>>(Wq, Wk, Wv, Wo, wqkvt, wot);
  k_gemm<0><<<dim3(32, 18), 256, 0, stream>>>(xb, wqkvt, qws, kws, vtws, nullptr);
  k_attn<<<dim3(24, 32), 256, 0, stream>>>(qws, kws, vtws, ows);
  k_gemm<1><<<dim3(32, 6), 256, 0, stream>>>(ows, wot, nullptr, nullptr, nullptr, out);
}